// Round 1
// baseline (252.808 us; speedup 1.0000x reference)
//
#include <hip/hip_runtime.h>
#include <hip/hip_bf16.h>

#define R_REL   8
#define C_DIM   64
#define K_DIM   576      // (R_REL+1)*C_DIM
#define KT_N    18       // K_DIM / 32
#define CT_N    4        // C_DIM / 16
#define TILE_M  16
#define K_PAD   584      // 576 + 8 bf16 pad -> row stride 1168 B (73*16B, conflict-free)

typedef __attribute__((ext_vector_type(8))) short bf16x8;
typedef __attribute__((ext_vector_type(4))) float f32x4;

static __device__ __forceinline__ unsigned short f2bf(float f) {
    union { float f; unsigned u; } v; v.f = f;
    unsigned r = v.u + 0x7FFFu + ((v.u >> 16) & 1u);   // RNE
    return (unsigned short)(r >> 16);
}

// Pack W [9][64][64] f32 -> bf16 MFMA B-fragments.
// Fragment f = kt*4+ct; slot t = f*64+lane holds 8 bf16:
//   W[kt*32 + (lane>>4)*8 + j][ct*16 + (lane&15)]
__global__ void pack_w_kernel(const float* __restrict__ w, unsigned int* __restrict__ wf) {
    int t = blockIdx.x * blockDim.x + threadIdx.x;
    if (t >= KT_N * CT_N * 64) return;
    int lane = t & 63;
    int ct   = (t >> 6) & 3;
    int kt   = t >> 8;
    int row0 = kt * 32 + (lane >> 4) * 8;
    int col  = ct * 16 + (lane & 15);
    unsigned short v[8];
#pragma unroll
    for (int j = 0; j < 8; ++j)
        v[j] = f2bf(w[(row0 + j) * C_DIM + col]);
    uint4 o;
    o.x = (unsigned)v[0] | ((unsigned)v[1] << 16);
    o.y = (unsigned)v[2] | ((unsigned)v[3] << 16);
    o.z = (unsigned)v[4] | ((unsigned)v[5] << 16);
    o.w = (unsigned)v[6] | ((unsigned)v[7] << 16);
    ((uint4*)wf)[t] = o;
}

__global__ __launch_bounds__(64) void rgcn_kernel(
    const float* __restrict__ x_feat,
    const float* __restrict__ bias,
    const int*   __restrict__ row_ptr,
    const int*   __restrict__ col_ind,
    const int*   __restrict__ edge_type,
    const unsigned short* __restrict__ wfrag,
    float* __restrict__ out,
    int n_nodes)
{
    __shared__ __align__(16) unsigned short xa[TILE_M][K_PAD];
    const int lane = threadIdx.x;          // 0..63 : channel in phase 1
    const int m0   = blockIdx.x * TILE_M;

    // ---------------- phase 1: aggregate 16 nodes into LDS (bf16) -------------
    for (int mi = 0; mi < TILE_M; ++mi) {
        const int n = m0 + mi;
        if (n >= n_nodes) {
            for (int k = lane; k < K_DIM; k += 64) xa[mi][k] = 0;
            continue;
        }
        const int base = row_ptr[n];
        const int deg  = row_ptr[n + 1] - base;
        float s0=0,s1=0,s2=0,s3=0,s4=0,s5=0,s6=0,s7=0;
        int   c0=0,c1=0,c2=0,c3=0,c4=0,c5=0,c6=0,c7=0;

        if (deg == 16) {
            float v[16]; int rel[16];
#pragma unroll
            for (int e = 0; e < 16; ++e) {
                int src = col_ind[base + e];
                rel[e]  = edge_type[base + e];
                v[e]    = x_feat[src * C_DIM + lane];
            }
#pragma unroll
            for (int e = 0; e < 16; ++e) {
                switch (rel[e]) {
                    case 0: s0 += v[e]; ++c0; break;
                    case 1: s1 += v[e]; ++c1; break;
                    case 2: s2 += v[e]; ++c2; break;
                    case 3: s3 += v[e]; ++c3; break;
                    case 4: s4 += v[e]; ++c4; break;
                    case 5: s5 += v[e]; ++c5; break;
                    case 6: s6 += v[e]; ++c6; break;
                    default: s7 += v[e]; ++c7; break;
                }
            }
        } else {
            for (int e = 0; e < deg; ++e) {
                int src = col_ind[base + e];
                int rel = edge_type[base + e];
                float vv = x_feat[src * C_DIM + lane];
                switch (rel) {
                    case 0: s0 += vv; ++c0; break;
                    case 1: s1 += vv; ++c1; break;
                    case 2: s2 += vv; ++c2; break;
                    case 3: s3 += vv; ++c3; break;
                    case 4: s4 += vv; ++c4; break;
                    case 5: s5 += vv; ++c5; break;
                    case 6: s6 += vv; ++c6; break;
                    default: s7 += vv; ++c7; break;
                }
            }
        }
        xa[mi][0 * C_DIM + lane] = f2bf(s0 * __fdividef(1.0f, (float)(c0 > 0 ? c0 : 1)));
        xa[mi][1 * C_DIM + lane] = f2bf(s1 * __fdividef(1.0f, (float)(c1 > 0 ? c1 : 1)));
        xa[mi][2 * C_DIM + lane] = f2bf(s2 * __fdividef(1.0f, (float)(c2 > 0 ? c2 : 1)));
        xa[mi][3 * C_DIM + lane] = f2bf(s3 * __fdividef(1.0f, (float)(c3 > 0 ? c3 : 1)));
        xa[mi][4 * C_DIM + lane] = f2bf(s4 * __fdividef(1.0f, (float)(c4 > 0 ? c4 : 1)));
        xa[mi][5 * C_DIM + lane] = f2bf(s5 * __fdividef(1.0f, (float)(c5 > 0 ? c5 : 1)));
        xa[mi][6 * C_DIM + lane] = f2bf(s6 * __fdividef(1.0f, (float)(c6 > 0 ? c6 : 1)));
        xa[mi][7 * C_DIM + lane] = f2bf(s7 * __fdividef(1.0f, (float)(c7 > 0 ? c7 : 1)));
        xa[mi][8 * C_DIM + lane] = f2bf(x_feat[n * C_DIM + lane]);   // self feature
    }
    __syncthreads();

    // ---------------- phase 2: [16 x 576] @ [576 x 64] via MFMA ---------------
    f32x4 acc0 = {0,0,0,0}, acc1 = {0,0,0,0}, acc2 = {0,0,0,0}, acc3 = {0,0,0,0};
    const int arow = lane & 15;
    const int kgrp = lane >> 4;
    const bf16x8* wf8 = (const bf16x8*)wfrag;
#pragma unroll
    for (int kt = 0; kt < KT_N; ++kt) {
        bf16x8 a = *(const bf16x8*)&xa[arow][kt * 32 + kgrp * 8];
        acc0 = __builtin_amdgcn_mfma_f32_16x16x32_bf16(a, wf8[(kt*4 + 0)*64 + lane], acc0, 0,0,0);
        acc1 = __builtin_amdgcn_mfma_f32_16x16x32_bf16(a, wf8[(kt*4 + 1)*64 + lane], acc1, 0,0,0);
        acc2 = __builtin_amdgcn_mfma_f32_16x16x32_bf16(a, wf8[(kt*4 + 2)*64 + lane], acc2, 0,0,0);
        acc3 = __builtin_amdgcn_mfma_f32_16x16x32_bf16(a, wf8[(kt*4 + 3)*64 + lane], acc3, 0,0,0);
    }

    // ---------------- epilogue: bias + store ----------------------------------
    const int col   = lane & 15;
    const int rbase = (lane >> 4) * 4;
    float b0 = bias[ 0 + col];
    float b1 = bias[16 + col];
    float b2 = bias[32 + col];
    float b3 = bias[48 + col];
#pragma unroll
    for (int j = 0; j < 4; ++j) {
        int n = m0 + rbase + j;
        if (n < n_nodes) {
            out[n * C_DIM +  0 + col] = acc0[j] + b0;
            out[n * C_DIM + 16 + col] = acc1[j] + b1;
            out[n * C_DIM + 32 + col] = acc2[j] + b2;
            out[n * C_DIM + 48 + col] = acc3[j] + b3;
        }
    }
}

extern "C" void kernel_launch(void* const* d_in, const int* in_sizes, int n_in,
                              void* d_out, int out_size, void* d_ws, size_t ws_size,
                              hipStream_t stream) {
    const float* x_feat    = (const float*)d_in[0];
    const float* weight    = (const float*)d_in[1];
    const float* bias      = (const float*)d_in[2];
    const int*   row_ptr   = (const int*)d_in[3];
    const int*   col_ind   = (const int*)d_in[4];
    const int*   edge_type = (const int*)d_in[5];
    float* out = (float*)d_out;

    const int n_nodes = in_sizes[3] - 1;

    unsigned int* wfrag = (unsigned int*)d_ws;   // 73728 bytes

    pack_w_kernel<<<(KT_N * CT_N * 64 + 255) / 256, 256, 0, stream>>>(weight, wfrag);

    const int nblocks = (n_nodes + TILE_M - 1) / TILE_M;
    rgcn_kernel<<<nblocks, 64, 0, stream>>>(x_feat, bias, row_ptr, col_ind, edge_type,
                                            (const unsigned short*)d_ws, out, n_nodes);
}

// Round 2
// 120.220 us; speedup vs baseline: 2.1029x; 2.1029x over previous
//
#include <hip/hip_runtime.h>
#include <hip/hip_bf16.h>

#define R_REL   8
#define C_DIM   64
#define K_DIM   576      // (R_REL+1)*C_DIM
#define KT_N    18       // K_DIM / 32
#define CT_N    4        // C_DIM / 16
#define TILE_M  16
#define K_PAD   584      // 576 + 8 bf16 pad -> row stride 1168 B
#define NW      4        // waves per block

typedef __attribute__((ext_vector_type(8))) short bf16x8;
typedef __attribute__((ext_vector_type(4))) float f32x4;

static __device__ __forceinline__ unsigned short f2bf(float f) {
    union { float f; unsigned u; } v; v.f = f;
    unsigned r = v.u + 0x7FFFu + ((v.u >> 16) & 1u);   // RNE
    return (unsigned short)(r >> 16);
}
static __device__ __forceinline__ float bf2f(unsigned short u) {
    union { unsigned u; float f; } v; v.u = ((unsigned)u) << 16;
    return v.f;
}

// Pack W [9][64][64] f32 -> bf16 MFMA B-fragments.
// Fragment f = kt*4+ct; slot t = f*64+lane holds 8 bf16:
//   W[kt*32 + (lane>>4)*8 + j][ct*16 + (lane&15)]
__global__ void pack_w_kernel(const float* __restrict__ w, unsigned int* __restrict__ wf) {
    int t = blockIdx.x * blockDim.x + threadIdx.x;
    if (t >= KT_N * CT_N * 64) return;
    int lane = t & 63;
    int ct   = (t >> 6) & 3;
    int kt   = t >> 8;
    int row0 = kt * 32 + (lane >> 4) * 8;
    int col  = ct * 16 + (lane & 15);
    unsigned short v[8];
#pragma unroll
    for (int j = 0; j < 8; ++j)
        v[j] = f2bf(w[(row0 + j) * C_DIM + col]);
    uint4 o;
    o.x = (unsigned)v[0] | ((unsigned)v[1] << 16);
    o.y = (unsigned)v[2] | ((unsigned)v[3] << 16);
    o.z = (unsigned)v[4] | ((unsigned)v[5] << 16);
    o.w = (unsigned)v[6] | ((unsigned)v[7] << 16);
    ((uint4*)wf)[t] = o;
}

// x_feat f32 -> bf16 (vectorized), so each edge gather reads 128B not 256B.
__global__ void cvt_x_kernel(const float* __restrict__ x, unsigned short* __restrict__ xb,
                             int n4) {
    int i = blockIdx.x * blockDim.x + threadIdx.x;
    if (i >= n4) return;
    float4 v = ((const float4*)x)[i];
    ushort4 o;
    o.x = f2bf(v.x); o.y = f2bf(v.y); o.z = f2bf(v.z); o.w = f2bf(v.w);
    ((ushort4*)xb)[i] = o;
}

#define ACCUM_SWITCH(RELV, VV)                                  \
    switch (RELV) {                                             \
        case 0: s0 += (VV); ++c0; break;                        \
        case 1: s1 += (VV); ++c1; break;                        \
        case 2: s2 += (VV); ++c2; break;                        \
        case 3: s3 += (VV); ++c3; break;                        \
        case 4: s4 += (VV); ++c4; break;                        \
        case 5: s5 += (VV); ++c5; break;                        \
        case 6: s6 += (VV); ++c6; break;                        \
        default: s7 += (VV); ++c7; break;                       \
    }

template<int USE_BF>
__global__ __launch_bounds__(256, 4) void rgcn_kernel(
    const float* __restrict__ x_feat,
    const unsigned short* __restrict__ xb,
    const float* __restrict__ bias,
    const int*   __restrict__ row_ptr,
    const int*   __restrict__ col_ind,
    const int*   __restrict__ edge_type,
    const unsigned short* __restrict__ wfrag,
    float* __restrict__ out,
    int n_nodes)
{
    __shared__ __align__(16) unsigned short xa[TILE_M][K_PAD];
    const int lane = threadIdx.x & 63;     // channel in phase 1
    const int w    = threadIdx.x >> 6;     // wave id 0..3
    const int m0   = blockIdx.x * TILE_M;

    // ---- phase 1: each wave aggregates 4 nodes into LDS (bf16) ----
    for (int mi = w * 4; mi < w * 4 + 4; ++mi) {
        const int n = m0 + mi;
        if (n >= n_nodes) {
            for (int k = lane; k < K_DIM; k += 64) xa[mi][k] = 0;
            continue;
        }
        const int base = row_ptr[n];
        const int deg  = row_ptr[n + 1] - base;
        float s0=0,s1=0,s2=0,s3=0,s4=0,s5=0,s6=0,s7=0;
        int   c0=0,c1=0,c2=0,c3=0,c4=0,c5=0,c6=0,c7=0;

        if (deg == 16) {
            int rel[16];
            if (USE_BF) {
                unsigned short uv[16];
#pragma unroll
                for (int e = 0; e < 16; ++e) {
                    int src = col_ind[base + e];
                    rel[e]  = edge_type[base + e];
                    uv[e]   = xb[src * C_DIM + lane];
                }
#pragma unroll
                for (int e = 0; e < 16; ++e) { float vv = bf2f(uv[e]); ACCUM_SWITCH(rel[e], vv) }
            } else {
                float v[16];
#pragma unroll
                for (int e = 0; e < 16; ++e) {
                    int src = col_ind[base + e];
                    rel[e]  = edge_type[base + e];
                    v[e]    = x_feat[src * C_DIM + lane];
                }
#pragma unroll
                for (int e = 0; e < 16; ++e) { ACCUM_SWITCH(rel[e], v[e]) }
            }
        } else {
            for (int e = 0; e < deg; ++e) {
                int src = col_ind[base + e];
                int rl  = edge_type[base + e];
                float vv = USE_BF ? bf2f(xb[src * C_DIM + lane])
                                  : x_feat[src * C_DIM + lane];
                ACCUM_SWITCH(rl, vv)
            }
        }
        xa[mi][0 * C_DIM + lane] = f2bf(s0 * __fdividef(1.0f, (float)(c0 > 0 ? c0 : 1)));
        xa[mi][1 * C_DIM + lane] = f2bf(s1 * __fdividef(1.0f, (float)(c1 > 0 ? c1 : 1)));
        xa[mi][2 * C_DIM + lane] = f2bf(s2 * __fdividef(1.0f, (float)(c2 > 0 ? c2 : 1)));
        xa[mi][3 * C_DIM + lane] = f2bf(s3 * __fdividef(1.0f, (float)(c3 > 0 ? c3 : 1)));
        xa[mi][4 * C_DIM + lane] = f2bf(s4 * __fdividef(1.0f, (float)(c4 > 0 ? c4 : 1)));
        xa[mi][5 * C_DIM + lane] = f2bf(s5 * __fdividef(1.0f, (float)(c5 > 0 ? c5 : 1)));
        xa[mi][6 * C_DIM + lane] = f2bf(s6 * __fdividef(1.0f, (float)(c6 > 0 ? c6 : 1)));
        xa[mi][7 * C_DIM + lane] = f2bf(s7 * __fdividef(1.0f, (float)(c7 > 0 ? c7 : 1)));
        xa[mi][8 * C_DIM + lane] = USE_BF ? xb[n * C_DIM + lane]
                                          : f2bf(x_feat[n * C_DIM + lane]);
    }
    __syncthreads();

    // ---- phase 2: [16 x 576] @ [576 x 64]; wave w owns C-tile ct=w ----
    const int ct   = w;
    f32x4 acc = {0,0,0,0};
    const int arow = lane & 15;
    const int kgrp = lane >> 4;
    const bf16x8* wf8 = (const bf16x8*)wfrag;
#pragma unroll
    for (int kt = 0; kt < KT_N; ++kt) {
        bf16x8 a = *(const bf16x8*)&xa[arow][kt * 32 + kgrp * 8];
        acc = __builtin_amdgcn_mfma_f32_16x16x32_bf16(a, wf8[(kt*4 + ct)*64 + lane], acc, 0,0,0);
    }

    // ---- epilogue ----
    const int col   = ct * 16 + (lane & 15);
    const float b   = bias[col];
    const int rbase = (lane >> 4) * 4;
#pragma unroll
    for (int j = 0; j < 4; ++j) {
        int n = m0 + rbase + j;
        if (n < n_nodes)
            out[n * C_DIM + col] = acc[j] + b;
    }
}

extern "C" void kernel_launch(void* const* d_in, const int* in_sizes, int n_in,
                              void* d_out, int out_size, void* d_ws, size_t ws_size,
                              hipStream_t stream) {
    const float* x_feat    = (const float*)d_in[0];
    const float* weight    = (const float*)d_in[1];
    const float* bias      = (const float*)d_in[2];
    const int*   row_ptr   = (const int*)d_in[3];
    const int*   col_ind   = (const int*)d_in[4];
    const int*   edge_type = (const int*)d_in[5];
    float* out = (float*)d_out;

    const int n_nodes = in_sizes[3] - 1;
    const int nblocks = (n_nodes + TILE_M - 1) / TILE_M;

    unsigned int* wfrag = (unsigned int*)d_ws;              // 73728 bytes
    const size_t wf_bytes = (size_t)KT_N * CT_N * 64 * 16;  // 73728
    const size_t xb_bytes = (size_t)n_nodes * C_DIM * 2;

    pack_w_kernel<<<(KT_N * CT_N * 64 + 255) / 256, 256, 0, stream>>>(weight, wfrag);

    if (ws_size >= wf_bytes + xb_bytes) {
        unsigned short* xb = (unsigned short*)((char*)d_ws + wf_bytes);
        int n4 = n_nodes * C_DIM / 4;
        cvt_x_kernel<<<(n4 + 255) / 256, 256, 0, stream>>>(x_feat, xb, n4);
        rgcn_kernel<1><<<nblocks, 256, 0, stream>>>(x_feat, xb, bias, row_ptr, col_ind,
                                                    edge_type, (const unsigned short*)d_ws,
                                                    out, n_nodes);
    } else {
        rgcn_kernel<0><<<nblocks, 256, 0, stream>>>(x_feat, nullptr, bias, row_ptr, col_ind,
                                                    edge_type, (const unsigned short*)d_ws,
                                                    out, n_nodes);
    }
}

// Round 3
// 116.020 us; speedup vs baseline: 2.1790x; 1.0362x over previous
//
#include <hip/hip_runtime.h>
#include <hip/hip_bf16.h>

#define R_REL   8
#define C_DIM   64
#define K_DIM   576      // (R_REL+1)*C_DIM
#define KT_N    18       // K_DIM / 32
#define CT_N    4        // C_DIM / 16
#define TILE_M  16
#define K_PAD   584      // 576 + 8 bf16 pad -> row stride 1168 B

typedef __attribute__((ext_vector_type(8))) short bf16x8;
typedef __attribute__((ext_vector_type(4))) float f32x4;

static __device__ __forceinline__ unsigned short f2bf(float f) {
    union { float f; unsigned u; } v; v.f = f;
    unsigned r = v.u + 0x7FFFu + ((v.u >> 16) & 1u);   // RNE
    return (unsigned short)(r >> 16);
}
static __device__ __forceinline__ float bf2f(unsigned u16) {
    union { unsigned u; float f; } v; v.u = u16 << 16;
    return v.f;
}

// Pack W [9][64][64] f32 -> bf16 MFMA B-fragments.
// Fragment f = kt*4+ct; slot t = f*64+lane holds 8 bf16:
//   W[kt*32 + (lane>>4)*8 + j][ct*16 + (lane&15)]
__global__ void pack_w_kernel(const float* __restrict__ w, unsigned int* __restrict__ wf) {
    int t = blockIdx.x * blockDim.x + threadIdx.x;
    if (t >= KT_N * CT_N * 64) return;
    int lane = t & 63;
    int ct   = (t >> 6) & 3;
    int kt   = t >> 8;
    int row0 = kt * 32 + (lane >> 4) * 8;
    int col  = ct * 16 + (lane & 15);
    unsigned short v[8];
#pragma unroll
    for (int j = 0; j < 8; ++j)
        v[j] = f2bf(w[(row0 + j) * C_DIM + col]);
    uint4 o;
    o.x = (unsigned)v[0] | ((unsigned)v[1] << 16);
    o.y = (unsigned)v[2] | ((unsigned)v[3] << 16);
    o.z = (unsigned)v[4] | ((unsigned)v[5] << 16);
    o.w = (unsigned)v[6] | ((unsigned)v[7] << 16);
    ((uint4*)wf)[t] = o;
}

// x_feat f32 -> bf16 (vectorized), so each edge gather reads 128B not 256B.
__global__ void cvt_x_kernel(const float* __restrict__ x, unsigned short* __restrict__ xb,
                             int n4) {
    int i = blockIdx.x * blockDim.x + threadIdx.x;
    if (i >= n4) return;
    float4 v = ((const float4*)x)[i];
    ushort4 o;
    o.x = f2bf(v.x); o.y = f2bf(v.y); o.z = f2bf(v.z); o.w = f2bf(v.w);
    ((ushort4*)xb)[i] = o;
}

#define ACCUM_SWITCH(RELV, VV)                                  \
    switch (RELV) {                                             \
        case 0: s0 += (VV); ++c0; break;                        \
        case 1: s1 += (VV); ++c1; break;                        \
        case 2: s2 += (VV); ++c2; break;                        \
        case 3: s3 += (VV); ++c3; break;                        \
        case 4: s4 += (VV); ++c4; break;                        \
        case 5: s5 += (VV); ++c5; break;                        \
        case 6: s6 += (VV); ++c6; break;                        \
        default: s7 += (VV); ++c7; break;                       \
    }

template<int USE_BF>
__global__ __launch_bounds__(256, 8) void rgcn_kernel(
    const float* __restrict__ x_feat,
    const unsigned short* __restrict__ xb,
    const float* __restrict__ bias,
    const int*   __restrict__ row_ptr,
    const int*   __restrict__ col_ind,
    const int*   __restrict__ edge_type,
    const unsigned short* __restrict__ wfrag,
    float* __restrict__ out,
    int n_nodes)
{
    __shared__ __align__(16) unsigned short xa[TILE_M][K_PAD];
    const int lane  = threadIdx.x & 63;    // channel in phase 1
    const int w     = threadIdx.x >> 6;    // wave id 0..3
    const int m0    = blockIdx.x * TILE_M;
    const int nbase = m0 + w * 4;          // this wave's 4 nodes

    // ---- hoisted per-node metadata + index vectors (all loads in flight) ----
    int basev[4], degv[4];
#pragma unroll
    for (int mi = 0; mi < 4; ++mi) {
        const int n = nbase + mi;
        if (n < n_nodes) {
            basev[mi] = row_ptr[n];
            degv[mi]  = row_ptr[n + 1] - basev[mi];
        } else {
            basev[mi] = 0;
            degv[mi]  = -1;                // sentinel: zero the row
        }
    }
    int colr[4], relr[4];
#pragma unroll
    for (int mi = 0; mi < 4; ++mi) {
        colr[mi] = col_ind[basev[mi] + (lane & 15)];
        relr[mi] = edge_type[basev[mi] + (lane & 15)];
    }

    // ---- phase 1: each wave aggregates its 4 nodes into LDS (bf16) ----
#pragma unroll
    for (int mi_ = 0; mi_ < 4; ++mi_) {
        const int mi = w * 4 + mi_;
        const int n  = nbase + mi_;
        if (degv[mi_] < 0) {               // out-of-range node: zero row
            for (int k = lane; k < K_DIM; k += 64) xa[mi][k] = 0;
            continue;
        }
        float s0=0,s1=0,s2=0,s3=0,s4=0,s5=0,s6=0,s7=0;
        int   c0=0,c1=0,c2=0,c3=0,c4=0,c5=0,c6=0,c7=0;

        if (degv[mi_] == 16) {
            // scalar-base gathers: src/rel broadcast to SGPRs via readlane
            unsigned uv[16];
#pragma unroll
            for (int e = 0; e < 16; ++e) {
                int src = __builtin_amdgcn_readlane(colr[mi_], e);
                if (USE_BF) {
                    uv[e] = xb[(size_t)src * C_DIM + lane];
                } else {
                    uv[e] = __float_as_uint(x_feat[(size_t)src * C_DIM + lane]);
                }
            }
#pragma unroll
            for (int e = 0; e < 16; ++e) {
                int rel = __builtin_amdgcn_readlane(relr[mi_], e);
                float vv = USE_BF ? bf2f(uv[e]) : __uint_as_float(uv[e]);
                ACCUM_SWITCH(rel, vv)
            }
        } else {
            const int base = basev[mi_];
            for (int e = 0; e < degv[mi_]; ++e) {
                int src = col_ind[base + e];
                int rl  = edge_type[base + e];
                float vv = USE_BF ? bf2f(xb[(size_t)src * C_DIM + lane])
                                  : x_feat[(size_t)src * C_DIM + lane];
                ACCUM_SWITCH(rl, vv)
            }
        }
        xa[mi][0 * C_DIM + lane] = f2bf(s0 * __fdividef(1.0f, (float)(c0 > 0 ? c0 : 1)));
        xa[mi][1 * C_DIM + lane] = f2bf(s1 * __fdividef(1.0f, (float)(c1 > 0 ? c1 : 1)));
        xa[mi][2 * C_DIM + lane] = f2bf(s2 * __fdividef(1.0f, (float)(c2 > 0 ? c2 : 1)));
        xa[mi][3 * C_DIM + lane] = f2bf(s3 * __fdividef(1.0f, (float)(c3 > 0 ? c3 : 1)));
        xa[mi][4 * C_DIM + lane] = f2bf(s4 * __fdividef(1.0f, (float)(c4 > 0 ? c4 : 1)));
        xa[mi][5 * C_DIM + lane] = f2bf(s5 * __fdividef(1.0f, (float)(c5 > 0 ? c5 : 1)));
        xa[mi][6 * C_DIM + lane] = f2bf(s6 * __fdividef(1.0f, (float)(c6 > 0 ? c6 : 1)));
        xa[mi][7 * C_DIM + lane] = f2bf(s7 * __fdividef(1.0f, (float)(c7 > 0 ? c7 : 1)));
        xa[mi][8 * C_DIM + lane] = USE_BF ? (unsigned short)xb[(size_t)n * C_DIM + lane]
                                          : f2bf(x_feat[(size_t)n * C_DIM + lane]);
    }
    __syncthreads();

    // ---- phase 2: [16 x 576] @ [576 x 64]; wave w owns C-tile ct=w ----
    const int ct   = w;
    f32x4 acc = {0,0,0,0};
    const int arow = lane & 15;
    const int kgrp = lane >> 4;
    const bf16x8* wf8 = (const bf16x8*)wfrag;
#pragma unroll
    for (int kt = 0; kt < KT_N; ++kt) {
        bf16x8 a = *(const bf16x8*)&xa[arow][kt * 32 + kgrp * 8];
        acc = __builtin_amdgcn_mfma_f32_16x16x32_bf16(a, wf8[(kt*4 + ct)*64 + lane], acc, 0,0,0);
    }

    // ---- epilogue ----
    const int col   = ct * 16 + (lane & 15);
    const float b   = bias[col];
    const int rbase = (lane >> 4) * 4;
#pragma unroll
    for (int j = 0; j < 4; ++j) {
        int n = m0 + rbase + j;
        if (n < n_nodes)
            out[n * C_DIM + col] = acc[j] + b;
    }
}

extern "C" void kernel_launch(void* const* d_in, const int* in_sizes, int n_in,
                              void* d_out, int out_size, void* d_ws, size_t ws_size,
                              hipStream_t stream) {
    const float* x_feat    = (const float*)d_in[0];
    const float* weight    = (const float*)d_in[1];
    const float* bias      = (const float*)d_in[2];
    const int*   row_ptr   = (const int*)d_in[3];
    const int*   col_ind   = (const int*)d_in[4];
    const int*   edge_type = (const int*)d_in[5];
    float* out = (float*)d_out;

    const int n_nodes = in_sizes[3] - 1;
    const int nblocks = (n_nodes + TILE_M - 1) / TILE_M;

    unsigned int* wfrag = (unsigned int*)d_ws;              // 73728 bytes
    const size_t wf_bytes = (size_t)KT_N * CT_N * 64 * 16;  // 73728
    const size_t xb_bytes = (size_t)n_nodes * C_DIM * 2;

    pack_w_kernel<<<(KT_N * CT_N * 64 + 255) / 256, 256, 0, stream>>>(weight, wfrag);

    if (ws_size >= wf_bytes + xb_bytes) {
        unsigned short* xb = (unsigned short*)((char*)d_ws + wf_bytes);
        int n4 = n_nodes * C_DIM / 4;
        cvt_x_kernel<<<(n4 + 255) / 256, 256, 0, stream>>>(x_feat, xb, n4);
        rgcn_kernel<1><<<nblocks, 256, 0, stream>>>(x_feat, xb, bias, row_ptr, col_ind,
                                                    edge_type, (const unsigned short*)d_ws,
                                                    out, n_nodes);
    } else {
        rgcn_kernel<0><<<nblocks, 256, 0, stream>>>(x_feat, nullptr, bias, row_ptr, col_ind,
                                                    edge_type, (const unsigned short*)d_ws,
                                                    out, n_nodes);
    }
}